// Round 2
// baseline (14808.430 us; speedup 1.0000x reference)
//
#include <hip/hip_runtime.h>
#include <math.h>
#include <float.h>
#include <limits.h>

#define BB 64        // batch (== wavefront size)
#define HID 768
#define VOCAB 30000
#define NG 3072      // 4*HID
#define TSTEPS 32
#define NB_LOG 235   // ceil(30000/128)
#define KSPLIT 8     // kg1 K-split (gates)

// ---------------------------------------------------------------------------
// Closed head stage 1: hid[b][r] = relu(feat[b] . c1W[r] + c1b[r]).
// ---------------------------------------------------------------------------
__global__ __launch_bounds__(256) void kc1(
    const float* __restrict__ feat, const float* __restrict__ c1W,
    const float* __restrict__ c1b, float* __restrict__ hid_ws)
{
    const int q = blockIdx.x, b = blockIdx.y;
    const int wave = threadIdx.x >> 6, lane = threadIdx.x & 63;
    float4 fr[3];
    const float4* frow = (const float4*)(feat + (size_t)b * HID);
    #pragma unroll
    for (int j = 0; j < 3; j++) fr[j] = frow[lane + 64 * j];

    #pragma unroll 2
    for (int rr = 0; rr < 32; rr++) {
        const int r = q * 128 + wave * 32 + rr;
        const float4* w = (const float4*)(c1W + (size_t)r * HID);
        float s = 0.f;
        #pragma unroll
        for (int j = 0; j < 3; j++) {
            float4 wv = w[lane + 64 * j];
            s += fr[j].x * wv.x + fr[j].y * wv.y + fr[j].z * wv.z + fr[j].w * wv.w;
        }
        #pragma unroll
        for (int o = 32; o; o >>= 1) s += __shfl_xor(s, o, 64);
        if (lane == 0) hid_ws[b * 512 + r] = fmaxf(s + c1b[r], 0.f);
    }
}

// Closed head stage 2.
__global__ __launch_bounds__(256) void kc2(
    const float* __restrict__ hid_ws, const float* __restrict__ c2W,
    const float* __restrict__ c2b, float* __restrict__ out)
{
    const int b = blockIdx.x, tid = threadIdx.x;
    __shared__ float red[2][256];
    float s0 = 0.f, s1 = 0.f;
    for (int r = tid; r < 512; r += 256) {
        float hv = hid_ws[b * 512 + r];
        s0 += hv * c2W[r];
        s1 += hv * c2W[512 + r];
    }
    red[0][tid] = s0; red[1][tid] = s1;
    __syncthreads();
    for (int st = 128; st; st >>= 1) {
        if (tid < st) { red[0][tid] += red[0][tid + st]; red[1][tid] += red[1][tid + st]; }
        __syncthreads();
    }
    if (tid == 0) {
        out[b * 2 + 0] = red[0][0] + c2b[0];
        out[b * 2 + 1] = red[1][0] + c2b[1];
    }
}

// ---------------------------------------------------------------------------
// Gates GEMM partial: grid (48, 8). nc = 64-col chunk of 3072; ks<4:
// x = emb[tok] @ W_ih K-quarter; ks>=4: h @ W_hh K-quarter. K=192/block.
// ---------------------------------------------------------------------------
__global__ __launch_bounds__(256) void kg1(
    int step, const int* __restrict__ tok_ws, const float* __restrict__ emb,
    const float* __restrict__ W_ih, const float* __restrict__ W_hh,
    const float* __restrict__ h_in, float* __restrict__ gpart)
{
    const int tid = threadIdx.x;
    const int nc = blockIdx.x;   // 0..47
    const int ks = blockIdx.y;   // 0..7
    __shared__ int tok_lds[BB];
    __shared__ float as[32][68];
    __shared__ float wsl[32][68];

    if (ks < 4 && tid < BB)
        tok_lds[tid] = (step == 0) ? 0 : tok_ws[tid];
    __syncthreads();

    const int ty = tid >> 4, tx = tid & 15;
    float acc[4][4] = {};

    for (int k0 = 0; k0 < 192; k0 += 32) {
        for (int i = tid; i < 512; i += 256) {   // A: 64 rows x 32 k
            int r = i >> 3, kq = i & 7;
            const float* base = (ks < 4)
                ? (emb + (size_t)tok_lds[r] * HID + ks * 192)
                : (h_in + (size_t)r * HID + (ks - 4) * 192);
            float4 v = *(const float4*)(base + k0 + kq * 4);
            as[kq*4+0][r] = v.x; as[kq*4+1][r] = v.y;
            as[kq*4+2][r] = v.z; as[kq*4+3][r] = v.w;
        }
        for (int i = tid; i < 512; i += 256) {   // W: 64 cols x 32 k
            int c = i >> 3, kq = i & 7;
            int gcol = nc * 64 + c;
            const float* wb = (ks < 4)
                ? (W_ih + (size_t)gcol * HID + ks * 192)
                : (W_hh + (size_t)gcol * HID + (ks - 4) * 192);
            float4 v = *(const float4*)(wb + k0 + kq * 4);
            wsl[kq*4+0][c] = v.x; wsl[kq*4+1][c] = v.y;
            wsl[kq*4+2][c] = v.z; wsl[kq*4+3][c] = v.w;
        }
        __syncthreads();
        #pragma unroll
        for (int kk = 0; kk < 32; kk++) {
            float4 av = *(const float4*)&as[kk][ty * 4];
            float4 wv = *(const float4*)&wsl[kk][tx * 4];
            acc[0][0] += av.x*wv.x; acc[0][1] += av.x*wv.y; acc[0][2] += av.x*wv.z; acc[0][3] += av.x*wv.w;
            acc[1][0] += av.y*wv.x; acc[1][1] += av.y*wv.y; acc[1][2] += av.y*wv.z; acc[1][3] += av.y*wv.w;
            acc[2][0] += av.z*wv.x; acc[2][1] += av.z*wv.y; acc[2][2] += av.z*wv.z; acc[2][3] += av.z*wv.w;
            acc[3][0] += av.w*wv.x; acc[3][1] += av.w*wv.y; acc[3][2] += av.w*wv.z; acc[3][3] += av.w*wv.w;
        }
        __syncthreads();
    }
    #pragma unroll
    for (int i = 0; i < 4; i++) {
        float4 v = make_float4(acc[i][0], acc[i][1], acc[i][2], acc[i][3]);
        *(float4*)(gpart + ((size_t)(ks * BB) + ty * 4 + i) * NG + nc * 64 + tx * 4) = v;
    }
}

// ---------------------------------------------------------------------------
// Cell: sum 8 K-partials (fixed order) + biases, LSTM update. Writes h
// b-major only (klog consumes b-major h directly).
// ---------------------------------------------------------------------------
__global__ __launch_bounds__(256) void kc(
    int step, const float* __restrict__ gpart, const float* __restrict__ b_ih,
    const float* __restrict__ b_hh, float* __restrict__ cbuf,
    float* __restrict__ h_out)
{
    int idx = blockIdx.x * 256 + threadIdx.x;   // < 64*768
    int b = idx / HID, j = idx % HID;
    float g4[4];
    #pragma unroll
    for (int g = 0; g < 4; g++) {
        int col = g * HID + j;
        float s = b_ih[col] + b_hh[col];
        #pragma unroll
        for (int ksd = 0; ksd < KSPLIT; ksd++)
            s += gpart[((size_t)ksd * BB + b) * NG + col];
        g4[g] = s;
    }
    float cprev = (step == 0) ? 0.f : cbuf[idx];
    float ig = 1.f / (1.f + expf(-g4[0]));
    float fg = 1.f / (1.f + expf(-g4[1]));
    float gg = tanhf(g4[2]);
    float og = 1.f / (1.f + expf(-g4[3]));
    float cn = fg * cprev + ig * gg;
    float hn = og * tanhf(cn);
    cbuf[idx] = cn;
    h_out[idx] = hn;
}

// ---------------------------------------------------------------------------
// Logits GEMM + fused argmax partial — lane-per-row broadcast structure.
//
// lane = batch row (M = 64 = wavefront). 1024 threads = 16 waves; wave w owns
// output columns [cb*128 + w*8, +8) over the FULL K=768 (no cross-team
// combine). B (outW) values are wave-uniform -> uniform-address ds_read_b128
// broadcasts (16B of LDS port per 4 FMAs, zero bank conflicts, linear layout
// so global_load_lds stages it directly). A (h) staged per K-chunk into LDS
// as [k4][b][4] whose 16B granules are contiguous in b-major h (gload_lds
// compatible); compute-side read is a fully contiguous conflict-free b128.
// K-chunk 64, double-buffered. Sync = plain __syncthreads(): at each sync
// the only outstanding VMEM is this wave's own stage of the chunk about to
// be computed, so the implicit vmcnt(0) drains exactly that; the NEXT
// chunk's stage is issued after the barrier and stays in flight under the
// current chunk's 512 FMA wave-instructions (T3-style overlap preserved,
// without raw-barrier reordering hazards).
// ---------------------------------------------------------------------------
#define KCH 64
#define NCH 12   // 768 / 64

__device__ __forceinline__ void stage16(const float* g, float* l)
{
    __builtin_amdgcn_global_load_lds(
        (const __attribute__((address_space(1))) void*)g,
        (__attribute__((address_space(3))) void*)l, 16, 0, 0);
}

__global__ __launch_bounds__(1024) void klog(
    const float* __restrict__ h, const float* __restrict__ outW,
    const float* __restrict__ outb, float* __restrict__ pval, int* __restrict__ pidx)
{
    // B: 128 cols x 64 k, layout [col][k] (col stride 64 floats). 32KB/buf.
    // A: 16 k4-groups x 64 b x 4, layout k4*256 + b*4 + j. 16KB/buf.
    __shared__ __attribute__((aligned(16))) float Bl[2][128 * KCH];
    __shared__ __attribute__((aligned(16))) float Al[2][16 * 256];
    __shared__ float candV[16 * 64];
    __shared__ int   candI[16 * 64];

    const int tid  = threadIdx.x;
    const int w    = tid >> 6;          // wave 0..15
    const int lane = tid & 63;          // = batch row
    const int cb = blockIdx.x;
    const int c0 = cb * 128;

    // ---- staging source pointers (per-lane) ----
    // B: per wave 2 calls of 1KB; call h covers cols w*8+4h .. +4,
    // lane -> col += lane/16, k = (lane%16)*4 .. +3.
    const int col0 = c0 + w * 8 + (lane >> 4);
    const int col1 = col0 + 4;
    const float* gB0 = outW + (size_t)((col0 < VOCAB) ? col0 : VOCAB - 1) * HID + (lane & 15) * 4;
    const float* gB1 = outW + (size_t)((col1 < VOCAB) ? col1 : VOCAB - 1) * HID + (lane & 15) * 4;
    // A: one call per wave; wave w covers k4 = w: lane -> row lane,
    // k-local = w*4 .. +3 (contiguous 16B in b-major h).
    const float* gA = h + (size_t)lane * HID + w * 4;

    float* lB0 = &Bl[0][w * 8 * KCH];
    float* lB1 = &Bl[1][w * 8 * KCH];
    float* lA0 = &Al[0][w * 256];
    float* lA1 = &Al[1][w * 256];

    auto stg = [&](int cn, float* lBb, float* lAb) {
        stage16(gB0 + (size_t)cn * KCH, lBb);
        stage16(gB1 + (size_t)cn * KCH, lBb + 4 * KCH);
        stage16(gA  + (size_t)cn * KCH, lAb);
    };

    float acc[8];
    #pragma unroll
    for (int j = 0; j < 8; j++) acc[j] = 0.f;

    auto compute = [&](const float* Bw, const float* Aw) {
        #pragma unroll
        for (int k4 = 0; k4 < 16; k4++) {
            float4 a4 = *(const float4*)(Aw + k4 * 256 + lane * 4);
            #pragma unroll
            for (int j = 0; j < 8; j++) {
                float4 bv = *(const float4*)(Bw + j * KCH + k4 * 4);  // uniform -> broadcast
                acc[j] = fmaf(a4.x, bv.x, acc[j]);
                acc[j] = fmaf(a4.y, bv.y, acc[j]);
                acc[j] = fmaf(a4.z, bv.z, acc[j]);
                acc[j] = fmaf(a4.w, bv.w, acc[j]);
            }
        }
    };

    // prologue: stage chunk 0 into buffer 0
    stg(0, lB0, lA0);

    for (int c = 0; c < NCH; c += 2) {
        // ---- even chunk c: buffer 0 ----
        __syncthreads();          // drains own stage(c) (vmcnt(0)); all waves
                                  // past their reads of buf1 from last iter
        stg(c + 1, lB1, lA1);     // c+1 <= 11 always valid; flies under compute
        compute(lB0, Al[0]);

        // ---- odd chunk c+1: buffer 1 ----
        __syncthreads();
        if (c + 2 < NCH) stg(c + 2, lB0, lA0);
        compute(lB1, Al[1]);
    }

    // ---- epilogue: bias + per-wave argmax over its 8 cols (full K done) ----
    const int nbase = c0 + w * 8;
    float bv = -FLT_MAX; int bi = INT_MAX;
    #pragma unroll
    for (int j = 0; j < 8; j++) {
        int cix = nbase + j;
        if (cix < VOCAB) {
            float v = acc[j] + outb[cix];
            if (v > bv) { bv = v; bi = cix; }   // ascending -> first occurrence
        }
    }
    candV[w * 64 + lane] = bv;
    candI[w * 64 + lane] = bi;
    __syncthreads();

    if (tid < BB) {
        float fv = -FLT_MAX; int fi = INT_MAX;
        #pragma unroll
        for (int ww = 0; ww < 16; ww++) {
            float v = candV[ww * 64 + tid]; int ix = candI[ww * 64 + tid];
            if (v > fv || (v == fv && ix < fi)) { fv = v; fi = ix; }
        }
        pval[tid * NB_LOG + cb] = fv;
        pidx[tid * NB_LOG + cb] = fi;
    }
}

// ---------------------------------------------------------------------------
// Finalize token for batch row b.
// ---------------------------------------------------------------------------
__global__ __launch_bounds__(256) void kfin(
    int step, const float* __restrict__ pval, const int* __restrict__ pidx,
    int* __restrict__ tok_ws, float* __restrict__ gen)
{
    const int b = blockIdx.x, tid = threadIdx.x;
    __shared__ float sv[256];
    __shared__ int   si[256];
    float bv = -FLT_MAX; int bi = INT_MAX;
    for (int p = tid; p < NB_LOG; p += 256) {
        float v = pval[b * NB_LOG + p]; int ix = pidx[b * NB_LOG + p];
        if (v > bv || (v == bv && ix < bi)) { bv = v; bi = ix; }
    }
    sv[tid] = bv; si[tid] = bi;
    __syncthreads();
    for (int st = 128; st; st >>= 1) {
        if (tid < st) {
            float v = sv[tid + st]; int ix = si[tid + st];
            if (v > sv[tid] || (v == sv[tid] && ix < si[tid])) { sv[tid] = v; si[tid] = ix; }
        }
        __syncthreads();
    }
    if (tid == 0) {
        tok_ws[b] = si[0];
        gen[b * TSTEPS + step] = (float)si[0];
    }
}

// ---------------------------------------------------------------------------
extern "C" void kernel_launch(void* const* d_in, const int* in_sizes, int n_in,
                              void* d_out, int out_size, void* d_ws, size_t ws_size,
                              hipStream_t stream)
{
    const float* feat = (const float*)d_in[0];
    const float* emb  = (const float*)d_in[1];
    const float* W_ih = (const float*)d_in[2];
    const float* W_hh = (const float*)d_in[3];
    const float* b_ih = (const float*)d_in[4];
    const float* b_hh = (const float*)d_in[5];
    const float* outW = (const float*)d_in[6];
    const float* outb = (const float*)d_in[7];
    const float* c1W  = (const float*)d_in[8];
    const float* c1b  = (const float*)d_in[9];
    const float* c2W  = (const float*)d_in[10];
    const float* c2b  = (const float*)d_in[11];
    (void)in_sizes; (void)n_in; (void)out_size; (void)ws_size;

    float* out = (float*)d_out;
    float* gen = out + BB * 2;                  // generated (64x32), as floats

    float* ws     = (float*)d_ws;
    float* hbuf   = ws;                               // 64*768  (b-major h)
    float* cbuf   = hbuf + BB * HID;                  // 64*768
    float* hT     = cbuf + BB * HID;                  // 768*64  (unused, layout kept)
    float* gpart  = hT + HID * 64;                    // 8*64*3072
    float* pval   = gpart + (size_t)KSPLIT * BB * NG; // 64*235
    int*   pidx   = (int*)(pval + BB * NB_LOG);       // 64*235
    int*   tok    = pidx + BB * NB_LOG;               // 64
    float* hid_ws = (float*)(tok + BB);               // 64*512

    kc1<<<dim3(4, BB), 256, 0, stream>>>(feat, c1W, c1b, hid_ws);
    kc2<<<BB, 256, 0, stream>>>(hid_ws, c2W, c2b, out);

    for (int t = 0; t < TSTEPS; t++) {
        const float* h_in = (t == 0) ? feat : hbuf;
        kg1<<<dim3(48, KSPLIT), 256, 0, stream>>>(t, tok, emb, W_ih, W_hh, h_in, gpart);
        kc<<<dim3(192), 256, 0, stream>>>(t, gpart, b_ih, b_hh, cbuf, hbuf);
        klog<<<dim3(NB_LOG), 1024, 0, stream>>>(hbuf, outW, outb, pval, pidx);
        kfin<<<BB, 256, 0, stream>>>(t, pval, pidx, tok, gen);
    }
}

// Round 3
// 6571.963 us; speedup vs baseline: 2.2533x; 2.2533x over previous
//
#include <hip/hip_runtime.h>
#include <math.h>
#include <float.h>
#include <limits.h>

#define BB 64        // batch (== wavefront size)
#define HID 768
#define VOCAB 30000
#define NG 3072      // 4*HID
#define TSTEPS 32
#define NBG 469      // ceil(30000/64) col-groups for klog
#define KSPLIT 8     // kg1 K-split (gates)

// ---------------------------------------------------------------------------
// Closed head stage 1: hid[b][r] = relu(feat[b] . c1W[r] + c1b[r]).
// ---------------------------------------------------------------------------
__global__ __launch_bounds__(256) void kc1(
    const float* __restrict__ feat, const float* __restrict__ c1W,
    const float* __restrict__ c1b, float* __restrict__ hid_ws)
{
    const int q = blockIdx.x, b = blockIdx.y;
    const int wave = threadIdx.x >> 6, lane = threadIdx.x & 63;
    float4 fr[3];
    const float4* frow = (const float4*)(feat + (size_t)b * HID);
    #pragma unroll
    for (int j = 0; j < 3; j++) fr[j] = frow[lane + 64 * j];

    #pragma unroll 2
    for (int rr = 0; rr < 32; rr++) {
        const int r = q * 128 + wave * 32 + rr;
        const float4* w = (const float4*)(c1W + (size_t)r * HID);
        float s = 0.f;
        #pragma unroll
        for (int j = 0; j < 3; j++) {
            float4 wv = w[lane + 64 * j];
            s += fr[j].x * wv.x + fr[j].y * wv.y + fr[j].z * wv.z + fr[j].w * wv.w;
        }
        #pragma unroll
        for (int o = 32; o; o >>= 1) s += __shfl_xor(s, o, 64);
        if (lane == 0) hid_ws[b * 512 + r] = fmaxf(s + c1b[r], 0.f);
    }
}

// Closed head stage 2.
__global__ __launch_bounds__(256) void kc2(
    const float* __restrict__ hid_ws, const float* __restrict__ c2W,
    const float* __restrict__ c2b, float* __restrict__ out)
{
    const int b = blockIdx.x, tid = threadIdx.x;
    __shared__ float red[2][256];
    float s0 = 0.f, s1 = 0.f;
    for (int r = tid; r < 512; r += 256) {
        float hv = hid_ws[b * 512 + r];
        s0 += hv * c2W[r];
        s1 += hv * c2W[512 + r];
    }
    red[0][tid] = s0; red[1][tid] = s1;
    __syncthreads();
    for (int st = 128; st; st >>= 1) {
        if (tid < st) { red[0][tid] += red[0][tid + st]; red[1][tid] += red[1][tid + st]; }
        __syncthreads();
    }
    if (tid == 0) {
        out[b * 2 + 0] = red[0][0] + c2b[0];
        out[b * 2 + 1] = red[1][0] + c2b[1];
    }
}

// ---------------------------------------------------------------------------
// Prep: hT[k][b] = feat[b][k]  (transposed h0 for klog).
// ---------------------------------------------------------------------------
__global__ __launch_bounds__(256) void kprep(
    const float* __restrict__ feat, float* __restrict__ hT)
{
    int idx = blockIdx.x * 256 + threadIdx.x;   // < 768*64
    int k = idx >> 6, b = idx & 63;
    hT[idx] = feat[b * HID + k];
}

// ---------------------------------------------------------------------------
// Gates GEMM partial: grid (48, 8). nc = 64-col chunk of 3072; ks<4:
// x = emb[tok] @ W_ih K-quarter; ks>=4: h @ W_hh K-quarter. K=192/block.
// ---------------------------------------------------------------------------
__global__ __launch_bounds__(256) void kg1(
    int step, const int* __restrict__ tok_ws, const float* __restrict__ emb,
    const float* __restrict__ W_ih, const float* __restrict__ W_hh,
    const float* __restrict__ h_in, float* __restrict__ gpart)
{
    const int tid = threadIdx.x;
    const int nc = blockIdx.x;   // 0..47
    const int ks = blockIdx.y;   // 0..7
    __shared__ int tok_lds[BB];
    __shared__ float as[32][68];
    __shared__ float wsl[32][68];

    if (ks < 4 && tid < BB)
        tok_lds[tid] = (step == 0) ? 0 : tok_ws[tid];
    __syncthreads();

    const int ty = tid >> 4, tx = tid & 15;
    float acc[4][4] = {};

    for (int k0 = 0; k0 < 192; k0 += 32) {
        for (int i = tid; i < 512; i += 256) {   // A: 64 rows x 32 k
            int r = i >> 3, kq = i & 7;
            const float* base = (ks < 4)
                ? (emb + (size_t)tok_lds[r] * HID + ks * 192)
                : (h_in + (size_t)r * HID + (ks - 4) * 192);
            float4 v = *(const float4*)(base + k0 + kq * 4);
            as[kq*4+0][r] = v.x; as[kq*4+1][r] = v.y;
            as[kq*4+2][r] = v.z; as[kq*4+3][r] = v.w;
        }
        for (int i = tid; i < 512; i += 256) {   // W: 64 cols x 32 k
            int c = i >> 3, kq = i & 7;
            int gcol = nc * 64 + c;
            const float* wb = (ks < 4)
                ? (W_ih + (size_t)gcol * HID + ks * 192)
                : (W_hh + (size_t)gcol * HID + (ks - 4) * 192);
            float4 v = *(const float4*)(wb + k0 + kq * 4);
            wsl[kq*4+0][c] = v.x; wsl[kq*4+1][c] = v.y;
            wsl[kq*4+2][c] = v.z; wsl[kq*4+3][c] = v.w;
        }
        __syncthreads();
        #pragma unroll
        for (int kk = 0; kk < 32; kk++) {
            float4 av = *(const float4*)&as[kk][ty * 4];
            float4 wv = *(const float4*)&wsl[kk][tx * 4];
            acc[0][0] += av.x*wv.x; acc[0][1] += av.x*wv.y; acc[0][2] += av.x*wv.z; acc[0][3] += av.x*wv.w;
            acc[1][0] += av.y*wv.x; acc[1][1] += av.y*wv.y; acc[1][2] += av.y*wv.z; acc[1][3] += av.y*wv.w;
            acc[2][0] += av.z*wv.x; acc[2][1] += av.z*wv.y; acc[2][2] += av.z*wv.z; acc[2][3] += av.z*wv.w;
            acc[3][0] += av.w*wv.x; acc[3][1] += av.w*wv.y; acc[3][2] += av.w*wv.z; acc[3][3] += av.w*wv.w;
        }
        __syncthreads();
    }
    #pragma unroll
    for (int i = 0; i < 4; i++) {
        float4 v = make_float4(acc[i][0], acc[i][1], acc[i][2], acc[i][3]);
        *(float4*)(gpart + ((size_t)(ks * BB) + ty * 4 + i) * NG + nc * 64 + tx * 4) = v;
    }
}

// ---------------------------------------------------------------------------
// Cell: sum 8 K-partials (fixed order) + biases, LSTM update. Writes h both
// b-major (for kg1) and transposed hT[k][b] (for klog).
// ---------------------------------------------------------------------------
__global__ __launch_bounds__(256) void kc(
    int step, const float* __restrict__ gpart, const float* __restrict__ b_ih,
    const float* __restrict__ b_hh, float* __restrict__ cbuf,
    float* __restrict__ h_out, float* __restrict__ hT)
{
    int idx = blockIdx.x * 256 + threadIdx.x;   // < 64*768
    int b = idx / HID, j = idx % HID;
    float g4[4];
    #pragma unroll
    for (int g = 0; g < 4; g++) {
        int col = g * HID + j;
        float s = b_ih[col] + b_hh[col];
        #pragma unroll
        for (int ksd = 0; ksd < KSPLIT; ksd++)
            s += gpart[((size_t)ksd * BB + b) * NG + col];
        g4[g] = s;
    }
    float cprev = (step == 0) ? 0.f : cbuf[idx];
    float ig = 1.f / (1.f + expf(-g4[0]));
    float fg = 1.f / (1.f + expf(-g4[1]));
    float gg = tanhf(g4[2]);
    float og = 1.f / (1.f + expf(-g4[3]));
    float cn = fg * cprev + ig * gg;
    float hn = og * tanhf(cn);
    cbuf[idx] = cn;
    h_out[idx] = hn;
    hT[j * 64 + b] = hn;
}

// ---------------------------------------------------------------------------
// Logits GEMM + fused argmax — lane = vocab column, rows via scalar path.
//
// Block = 512 thr = 8 waves; block owns 64 cols (cb*64 + lane), wave w owns
// rows [w*8, w*8+8). No LDS in the main loop:
//   A: hT[k][w*8 .. w*8+8) = 32 contiguous bytes at a wave-UNIFORM address
//      (readfirstlane'd) -> s_load_dwordx8 into SGPRs; v_fmac reads the
//      broadcast operand straight from SGPR (1 SGPR/VALU rule ok).
//   B: outW[col][k4*4..+4) per-lane float4; the 64 lanes' 64B lines are fully
//      consumed over 4 consecutive k4 and shared by all 8 waves via L1
//      (4KB working set) -> outW read ~once (92MB/dispatch).
// acc[8] per thread, named double-buffered prefetch (no runtime-indexed
// arrays -> no scratch). Epilogue: per-row 64-lane shuffle argmax.
// ---------------------------------------------------------------------------
typedef float vf8 __attribute__((ext_vector_type(8)));

__global__ __launch_bounds__(512) void klog(
    const float* __restrict__ hT, const float* __restrict__ outW,
    const float* __restrict__ outb, float* __restrict__ pval, int* __restrict__ pidx)
{
    const int tid  = threadIdx.x;
    const int wv   = __builtin_amdgcn_readfirstlane(tid >> 6);  // wave 0..7 (uniform)
    const int lane = tid & 63;
    const int cb   = blockIdx.x;
    const int col  = cb * 64 + lane;
    const int colc = (col < VOCAB) ? col : (VOCAB - 1);

    const float4* brow = (const float4*)(outW + (size_t)colc * HID);  // per-lane
    const vf8*    A    = (const vf8*)hT;   // A[k*8 + wv] = hT[k][wv*8 .. +8)

    float acc[8];
    #pragma unroll
    for (int r = 0; r < 8; r++) acc[r] = 0.f;

    // named double buffers: (a0,b0) <- k4, (a1,b1) <- k4+1
    vf8 a0[4], a1[4];
    float4 b0, b1;
    #pragma unroll
    for (int kk = 0; kk < 4; kk++) a0[kk] = A[(0 * 4 + kk) * 8 + wv];
    b0 = brow[0];
    #pragma unroll
    for (int kk = 0; kk < 4; kk++) a1[kk] = A[(1 * 4 + kk) * 8 + wv];
    b1 = brow[1];

    for (int k4 = 0; k4 < 192; k4 += 2) {
        // ---- compute k4 from (a0,b0) ----
        {
            float bv[4] = {b0.x, b0.y, b0.z, b0.w};
            #pragma unroll
            for (int kk = 0; kk < 4; kk++)
                #pragma unroll
                for (int r = 0; r < 8; r++)
                    acc[r] = fmaf(a0[kk][r], bv[kk], acc[r]);
        }
        if (k4 + 2 < 192) {   // prefetch k4+2 -> (a0,b0); hides under k4+1 compute
            #pragma unroll
            for (int kk = 0; kk < 4; kk++) a0[kk] = A[((k4 + 2) * 4 + kk) * 8 + wv];
            b0 = brow[k4 + 2];
        }
        // ---- compute k4+1 from (a1,b1) ----
        {
            float bv[4] = {b1.x, b1.y, b1.z, b1.w};
            #pragma unroll
            for (int kk = 0; kk < 4; kk++)
                #pragma unroll
                for (int r = 0; r < 8; r++)
                    acc[r] = fmaf(a1[kk][r], bv[kk], acc[r]);
        }
        if (k4 + 3 < 192) {   // prefetch k4+3 -> (a1,b1)
            #pragma unroll
            for (int kk = 0; kk < 4; kk++) a1[kk] = A[((k4 + 3) * 4 + kk) * 8 + wv];
            b1 = brow[k4 + 3];
        }
    }

    // ---- epilogue: bias + per-row shuffle argmax over the wave's 64 cols ----
    const bool valid = (col < VOCAB);
    const float ob = outb[colc];
    const int r0 = wv * 8;
    #pragma unroll
    for (int i = 0; i < 8; i++) {
        float v  = valid ? (acc[i] + ob) : -FLT_MAX;
        int   ix = valid ? col : INT_MAX;
        #pragma unroll
        for (int off = 32; off; off >>= 1) {
            float vv = __shfl_xor(v, off, 64);
            int   ii = __shfl_xor(ix, off, 64);
            if (vv > v || (vv == v && ii < ix)) { v = vv; ix = ii; }
        }
        if (lane == 0) {
            pval[(size_t)(r0 + i) * NBG + cb] = v;
            pidx[(size_t)(r0 + i) * NBG + cb] = ix;
        }
    }
}

// ---------------------------------------------------------------------------
// Finalize token for batch row b.
// ---------------------------------------------------------------------------
__global__ __launch_bounds__(256) void kfin(
    int step, const float* __restrict__ pval, const int* __restrict__ pidx,
    int* __restrict__ tok_ws, float* __restrict__ gen)
{
    const int b = blockIdx.x, tid = threadIdx.x;
    __shared__ float sv[256];
    __shared__ int   si[256];
    float bv = -FLT_MAX; int bi = INT_MAX;
    for (int p = tid; p < NBG; p += 256) {
        float v = pval[(size_t)b * NBG + p]; int ix = pidx[(size_t)b * NBG + p];
        if (v > bv || (v == bv && ix < bi)) { bv = v; bi = ix; }
    }
    sv[tid] = bv; si[tid] = bi;
    __syncthreads();
    for (int st = 128; st; st >>= 1) {
        if (tid < st) {
            float v = sv[tid + st]; int ix = si[tid + st];
            if (v > sv[tid] || (v == sv[tid] && ix < si[tid])) { sv[tid] = v; si[tid] = ix; }
        }
        __syncthreads();
    }
    if (tid == 0) {
        tok_ws[b] = si[0];
        gen[b * TSTEPS + step] = (float)si[0];
    }
}

// ---------------------------------------------------------------------------
extern "C" void kernel_launch(void* const* d_in, const int* in_sizes, int n_in,
                              void* d_out, int out_size, void* d_ws, size_t ws_size,
                              hipStream_t stream)
{
    const float* feat = (const float*)d_in[0];
    const float* emb  = (const float*)d_in[1];
    const float* W_ih = (const float*)d_in[2];
    const float* W_hh = (const float*)d_in[3];
    const float* b_ih = (const float*)d_in[4];
    const float* b_hh = (const float*)d_in[5];
    const float* outW = (const float*)d_in[6];
    const float* outb = (const float*)d_in[7];
    const float* c1W  = (const float*)d_in[8];
    const float* c1b  = (const float*)d_in[9];
    const float* c2W  = (const float*)d_in[10];
    const float* c2b  = (const float*)d_in[11];
    (void)in_sizes; (void)n_in; (void)out_size; (void)ws_size;

    float* out = (float*)d_out;
    float* gen = out + BB * 2;                  // generated (64x32), as floats

    float* ws     = (float*)d_ws;
    float* hbuf   = ws;                               // 64*768  (b-major h)
    float* cbuf   = hbuf + BB * HID;                  // 64*768
    float* hT     = cbuf + BB * HID;                  // 768*64  (k-major h)
    float* gpart  = hT + HID * 64;                    // 8*64*3072
    float* pval   = gpart + (size_t)KSPLIT * BB * NG; // 64*469
    int*   pidx   = (int*)(pval + BB * NBG);          // 64*469
    int*   tok    = pidx + BB * NBG;                  // 64
    float* hid_ws = (float*)(tok + BB);               // 64*512

    kc1<<<dim3(4, BB), 256, 0, stream>>>(feat, c1W, c1b, hid_ws);
    kc2<<<BB, 256, 0, stream>>>(hid_ws, c2W, c2b, out);
    kprep<<<dim3(HID * 64 / 256), 256, 0, stream>>>(feat, hT);

    for (int t = 0; t < TSTEPS; t++) {
        const float* h_in = (t == 0) ? feat : hbuf;
        kg1<<<dim3(48, KSPLIT), 256, 0, stream>>>(t, tok, emb, W_ih, W_hh, h_in, gpart);
        kc<<<dim3(192), 256, 0, stream>>>(t, gpart, b_ih, b_hh, cbuf, hbuf, hT);
        klog<<<dim3(NBG), 512, 0, stream>>>(hT, outW, outb, pval, pidx);
        kfin<<<BB, 256, 0, stream>>>(t, pval, pidx, tok, gen);
    }
}

// Round 4
// 4218.322 us; speedup vs baseline: 3.5105x; 1.5580x over previous
//
#include <hip/hip_runtime.h>
#include <math.h>
#include <float.h>
#include <limits.h>

#define BB 64        // batch (== wavefront size)
#define HID 768
#define VOCAB 30000
#define NG 3072      // 4*HID
#define TSTEPS 32
#define NBG 469      // ceil(30000/64) col-groups for klog
#define KSPLIT 8     // kg1 K-split (gates)

// ---------------------------------------------------------------------------
// Closed head stage 1: hid[b][r] = relu(feat[b] . c1W[r] + c1b[r]).
// ---------------------------------------------------------------------------
__global__ __launch_bounds__(256) void kc1(
    const float* __restrict__ feat, const float* __restrict__ c1W,
    const float* __restrict__ c1b, float* __restrict__ hid_ws)
{
    const int q = blockIdx.x, b = blockIdx.y;
    const int wave = threadIdx.x >> 6, lane = threadIdx.x & 63;
    float4 fr[3];
    const float4* frow = (const float4*)(feat + (size_t)b * HID);
    #pragma unroll
    for (int j = 0; j < 3; j++) fr[j] = frow[lane + 64 * j];

    #pragma unroll 2
    for (int rr = 0; rr < 32; rr++) {
        const int r = q * 128 + wave * 32 + rr;
        const float4* w = (const float4*)(c1W + (size_t)r * HID);
        float s = 0.f;
        #pragma unroll
        for (int j = 0; j < 3; j++) {
            float4 wv = w[lane + 64 * j];
            s += fr[j].x * wv.x + fr[j].y * wv.y + fr[j].z * wv.z + fr[j].w * wv.w;
        }
        #pragma unroll
        for (int o = 32; o; o >>= 1) s += __shfl_xor(s, o, 64);
        if (lane == 0) hid_ws[b * 512 + r] = fmaxf(s + c1b[r], 0.f);
    }
}

// Closed head stage 2.
__global__ __launch_bounds__(256) void kc2(
    const float* __restrict__ hid_ws, const float* __restrict__ c2W,
    const float* __restrict__ c2b, float* __restrict__ out)
{
    const int b = blockIdx.x, tid = threadIdx.x;
    __shared__ float red[2][256];
    float s0 = 0.f, s1 = 0.f;
    for (int r = tid; r < 512; r += 256) {
        float hv = hid_ws[b * 512 + r];
        s0 += hv * c2W[r];
        s1 += hv * c2W[512 + r];
    }
    red[0][tid] = s0; red[1][tid] = s1;
    __syncthreads();
    for (int st = 128; st; st >>= 1) {
        if (tid < st) { red[0][tid] += red[0][tid + st]; red[1][tid] += red[1][tid + st]; }
        __syncthreads();
    }
    if (tid == 0) {
        out[b * 2 + 0] = red[0][0] + c2b[0];
        out[b * 2 + 1] = red[1][0] + c2b[1];
    }
}

// ---------------------------------------------------------------------------
// Prep: hT[k][b] = feat[b][k]  (transposed h0 for klog).
// ---------------------------------------------------------------------------
__global__ __launch_bounds__(256) void kprep(
    const float* __restrict__ feat, float* __restrict__ hT)
{
    int idx = blockIdx.x * 256 + threadIdx.x;   // < 768*64
    int k = idx >> 6, b = idx & 63;
    hT[idx] = feat[b * HID + k];
}

// ---------------------------------------------------------------------------
// Gates GEMM partial: grid (48, 8). nc = 64-col chunk of 3072; ks<4:
// x = emb[tok] @ W_ih K-quarter; ks>=4: h @ W_hh K-quarter. K=192/block.
// ---------------------------------------------------------------------------
__global__ __launch_bounds__(256) void kg1(
    int step, const int* __restrict__ tok_ws, const float* __restrict__ emb,
    const float* __restrict__ W_ih, const float* __restrict__ W_hh,
    const float* __restrict__ h_in, float* __restrict__ gpart)
{
    const int tid = threadIdx.x;
    const int nc = blockIdx.x;   // 0..47
    const int ks = blockIdx.y;   // 0..7
    __shared__ int tok_lds[BB];
    __shared__ float as[32][68];
    __shared__ float wsl[32][68];

    if (ks < 4 && tid < BB)
        tok_lds[tid] = (step == 0) ? 0 : tok_ws[tid];
    __syncthreads();

    const int ty = tid >> 4, tx = tid & 15;
    float acc[4][4] = {};

    for (int k0 = 0; k0 < 192; k0 += 32) {
        for (int i = tid; i < 512; i += 256) {   // A: 64 rows x 32 k
            int r = i >> 3, kq = i & 7;
            const float* base = (ks < 4)
                ? (emb + (size_t)tok_lds[r] * HID + ks * 192)
                : (h_in + (size_t)r * HID + (ks - 4) * 192);
            float4 v = *(const float4*)(base + k0 + kq * 4);
            as[kq*4+0][r] = v.x; as[kq*4+1][r] = v.y;
            as[kq*4+2][r] = v.z; as[kq*4+3][r] = v.w;
        }
        for (int i = tid; i < 512; i += 256) {   // W: 64 cols x 32 k
            int c = i >> 3, kq = i & 7;
            int gcol = nc * 64 + c;
            const float* wb = (ks < 4)
                ? (W_ih + (size_t)gcol * HID + ks * 192)
                : (W_hh + (size_t)gcol * HID + (ks - 4) * 192);
            float4 v = *(const float4*)(wb + k0 + kq * 4);
            wsl[kq*4+0][c] = v.x; wsl[kq*4+1][c] = v.y;
            wsl[kq*4+2][c] = v.z; wsl[kq*4+3][c] = v.w;
        }
        __syncthreads();
        #pragma unroll
        for (int kk = 0; kk < 32; kk++) {
            float4 av = *(const float4*)&as[kk][ty * 4];
            float4 wv = *(const float4*)&wsl[kk][tx * 4];
            acc[0][0] += av.x*wv.x; acc[0][1] += av.x*wv.y; acc[0][2] += av.x*wv.z; acc[0][3] += av.x*wv.w;
            acc[1][0] += av.y*wv.x; acc[1][1] += av.y*wv.y; acc[1][2] += av.y*wv.z; acc[1][3] += av.y*wv.w;
            acc[2][0] += av.z*wv.x; acc[2][1] += av.z*wv.y; acc[2][2] += av.z*wv.z; acc[2][3] += av.z*wv.w;
            acc[3][0] += av.w*wv.x; acc[3][1] += av.w*wv.y; acc[3][2] += av.w*wv.z; acc[3][3] += av.w*wv.w;
        }
        __syncthreads();
    }
    #pragma unroll
    for (int i = 0; i < 4; i++) {
        float4 v = make_float4(acc[i][0], acc[i][1], acc[i][2], acc[i][3]);
        *(float4*)(gpart + ((size_t)(ks * BB) + ty * 4 + i) * NG + nc * 64 + tx * 4) = v;
    }
}

// ---------------------------------------------------------------------------
// Cell: sum 8 K-partials (fixed order) + biases, LSTM update. Writes h both
// b-major (for kg1) and transposed hT[k][b] (for klog).
// ---------------------------------------------------------------------------
__global__ __launch_bounds__(256) void kc(
    int step, const float* __restrict__ gpart, const float* __restrict__ b_ih,
    const float* __restrict__ b_hh, float* __restrict__ cbuf,
    float* __restrict__ h_out, float* __restrict__ hT)
{
    int idx = blockIdx.x * 256 + threadIdx.x;   // < 64*768
    int b = idx / HID, j = idx % HID;
    float g4[4];
    #pragma unroll
    for (int g = 0; g < 4; g++) {
        int col = g * HID + j;
        float s = b_ih[col] + b_hh[col];
        #pragma unroll
        for (int ksd = 0; ksd < KSPLIT; ksd++)
            s += gpart[((size_t)ksd * BB + b) * NG + col];
        g4[g] = s;
    }
    float cprev = (step == 0) ? 0.f : cbuf[idx];
    float ig = 1.f / (1.f + expf(-g4[0]));
    float fg = 1.f / (1.f + expf(-g4[1]));
    float gg = tanhf(g4[2]);
    float og = 1.f / (1.f + expf(-g4[3]));
    float cn = fg * cprev + ig * gg;
    float hn = og * tanhf(cn);
    cbuf[idx] = cn;
    h_out[idx] = hn;
    hT[j * 64 + b] = hn;
}

// ---------------------------------------------------------------------------
// Logits GEMM + fused argmax — kg1-clone structure (the proven-fast fp32
// GEMM in this file: ~75% of VALU floor).
//
// Grid = 469 blocks x 256 thr; block = 64 batch rows x 64 vocab cols, full
// K=768 as 24 chunks of 32. LDS = as[32][68] (A, [k][m]) + bs[32][68]
// (B, [k][n]) = 17.4 KB -> ~2 blocks/CU. Stride 68 floats = 272 B keeps
// float4 rows 16B-aligned; compute reads are 16-address broadcast (A) /
// 2-way (B) = conflict-free. Register-prefetch split (T14): chunk c+1's
// global loads are issued before compute(c) and written to LDS after the
// barrier, so HBM/L2 latency hides under the 512-FMA compute phase.
// Epilogue: bias + per-row argmax via 16-lane shuffle (threads sharing ty
// hold one row's 64 cols), deterministic first-occurrence tie-break.
// ---------------------------------------------------------------------------
__global__ __launch_bounds__(256) void klog(
    const float* __restrict__ hT, const float* __restrict__ outW,
    const float* __restrict__ outb, float* __restrict__ pval, int* __restrict__ pidx)
{
    __shared__ float as[32][68];
    __shared__ float bs[32][68];

    const int tid = threadIdx.x;
    const int cb  = blockIdx.x;
    const int c0  = cb * 64;
    const int ty  = tid >> 4, tx = tid & 15;

    // staging coordinates (fixed per thread)
    const int ak0 = tid >> 4;          // A: j=0 row (k)   0..15
    const int ab4 = (tid & 15) * 4;    //    b offset
    const int bc  = tid >> 3;          // B: col 0..31 (j=0)
    const int bkq = tid & 7;           //    k-quarter

    const int bcol0 = c0 + bc;
    const int bcol1 = c0 + bc + 32;
    const float* bW0 = outW + (size_t)((bcol0 < VOCAB) ? bcol0 : VOCAB - 1) * HID + bkq * 4;
    const float* bW1 = outW + (size_t)((bcol1 < VOCAB) ? bcol1 : VOCAB - 1) * HID + bkq * 4;

    float acc[4][4] = {};
    float4 pa0, pa1, pb0, pb1;

    // loads for chunk c -> regs
    auto ld = [&](int c, float4& a0, float4& a1, float4& b0, float4& b1) {
        const float* hchunk = hT + (size_t)c * 32 * 64;
        a0 = *(const float4*)(hchunk + (ak0)      * 64 + ab4);
        a1 = *(const float4*)(hchunk + (ak0 + 16) * 64 + ab4);
        b0 = *(const float4*)(bW0 + c * 32);
        b1 = *(const float4*)(bW1 + c * 32);
    };
    // regs -> LDS
    auto wr = [&](float4 a0, float4 a1, float4 b0, float4 b1) {
        *(float4*)&as[ak0][ab4]      = a0;
        *(float4*)&as[ak0 + 16][ab4] = a1;
        bs[bkq*4+0][bc] = b0.x; bs[bkq*4+1][bc] = b0.y;
        bs[bkq*4+2][bc] = b0.z; bs[bkq*4+3][bc] = b0.w;
        bs[bkq*4+0][bc+32] = b1.x; bs[bkq*4+1][bc+32] = b1.y;
        bs[bkq*4+2][bc+32] = b1.z; bs[bkq*4+3][bc+32] = b1.w;
    };

    ld(0, pa0, pa1, pb0, pb1);
    wr(pa0, pa1, pb0, pb1);
    __syncthreads();

    for (int c = 0; c < 24; c++) {
        if (c + 1 < 24) ld(c + 1, pa0, pa1, pb0, pb1);   // flies under compute
        #pragma unroll
        for (int kk = 0; kk < 32; kk++) {
            float4 av = *(const float4*)&as[kk][ty * 4];   // broadcast
            float4 wv = *(const float4*)&bs[kk][tx * 4];   // 2-way (free)
            acc[0][0] = fmaf(av.x, wv.x, acc[0][0]); acc[0][1] = fmaf(av.x, wv.y, acc[0][1]);
            acc[0][2] = fmaf(av.x, wv.z, acc[0][2]); acc[0][3] = fmaf(av.x, wv.w, acc[0][3]);
            acc[1][0] = fmaf(av.y, wv.x, acc[1][0]); acc[1][1] = fmaf(av.y, wv.y, acc[1][1]);
            acc[1][2] = fmaf(av.y, wv.z, acc[1][2]); acc[1][3] = fmaf(av.y, wv.w, acc[1][3]);
            acc[2][0] = fmaf(av.z, wv.x, acc[2][0]); acc[2][1] = fmaf(av.z, wv.y, acc[2][1]);
            acc[2][2] = fmaf(av.z, wv.z, acc[2][2]); acc[2][3] = fmaf(av.z, wv.w, acc[2][3]);
            acc[3][0] = fmaf(av.w, wv.x, acc[3][0]); acc[3][1] = fmaf(av.w, wv.y, acc[3][1]);
            acc[3][2] = fmaf(av.w, wv.z, acc[3][2]); acc[3][3] = fmaf(av.w, wv.w, acc[3][3]);
        }
        __syncthreads();
        if (c + 1 < 24) {
            wr(pa0, pa1, pb0, pb1);
            __syncthreads();
        }
    }

    // ---- epilogue: bias + per-row argmax over the block's 64 cols ----
    float ob[4];
    #pragma unroll
    for (int j = 0; j < 4; j++) {
        int cix = c0 + tx * 4 + j;
        ob[j] = (cix < VOCAB) ? outb[cix] : 0.f;
    }
    #pragma unroll
    for (int i = 0; i < 4; i++) {
        const int row = ty * 4 + i;
        float bv = -FLT_MAX; int bi = INT_MAX;
        #pragma unroll
        for (int j = 0; j < 4; j++) {
            int cix = c0 + tx * 4 + j;
            if (cix < VOCAB) {
                float v = acc[i][j] + ob[j];
                if (v > bv) { bv = v; bi = cix; }   // j ascending -> first occurrence
            }
        }
        // reduce across the 16-lane tx-group (lanes ty*16 .. ty*16+15)
        #pragma unroll
        for (int off = 1; off < 16; off <<= 1) {
            float vv = __shfl_xor(bv, off, 64);
            int   ii = __shfl_xor(bi, off, 64);
            if (vv > bv || (vv == bv && ii < bi)) { bv = vv; bi = ii; }
        }
        if (tx == 0) {
            pval[(size_t)row * NBG + cb] = bv;
            pidx[(size_t)row * NBG + cb] = bi;
        }
    }
}

// ---------------------------------------------------------------------------
// Finalize token for batch row b.
// ---------------------------------------------------------------------------
__global__ __launch_bounds__(256) void kfin(
    int step, const float* __restrict__ pval, const int* __restrict__ pidx,
    int* __restrict__ tok_ws, float* __restrict__ gen)
{
    const int b = blockIdx.x, tid = threadIdx.x;
    __shared__ float sv[256];
    __shared__ int   si[256];
    float bv = -FLT_MAX; int bi = INT_MAX;
    for (int p = tid; p < NBG; p += 256) {
        float v = pval[(size_t)b * NBG + p]; int ix = pidx[(size_t)b * NBG + p];
        if (v > bv || (v == bv && ix < bi)) { bv = v; bi = ix; }
    }
    sv[tid] = bv; si[tid] = bi;
    __syncthreads();
    for (int st = 128; st; st >>= 1) {
        if (tid < st) {
            float v = sv[tid + st]; int ix = si[tid + st];
            if (v > sv[tid] || (v == sv[tid] && ix < si[tid])) { sv[tid] = v; si[tid] = ix; }
        }
        __syncthreads();
    }
    if (tid == 0) {
        tok_ws[b] = si[0];
        gen[b * TSTEPS + step] = (float)si[0];
    }
}

// ---------------------------------------------------------------------------
extern "C" void kernel_launch(void* const* d_in, const int* in_sizes, int n_in,
                              void* d_out, int out_size, void* d_ws, size_t ws_size,
                              hipStream_t stream)
{
    const float* feat = (const float*)d_in[0];
    const float* emb  = (const float*)d_in[1];
    const float* W_ih = (const float*)d_in[2];
    const float* W_hh = (const float*)d_in[3];
    const float* b_ih = (const float*)d_in[4];
    const float* b_hh = (const float*)d_in[5];
    const float* outW = (const float*)d_in[6];
    const float* outb = (const float*)d_in[7];
    const float* c1W  = (const float*)d_in[8];
    const float* c1b  = (const float*)d_in[9];
    const float* c2W  = (const float*)d_in[10];
    const float* c2b  = (const float*)d_in[11];
    (void)in_sizes; (void)n_in; (void)out_size; (void)ws_size;

    float* out = (float*)d_out;
    float* gen = out + BB * 2;                  // generated (64x32), as floats

    float* ws     = (float*)d_ws;
    float* hbuf   = ws;                               // 64*768  (b-major h)
    float* cbuf   = hbuf + BB * HID;                  // 64*768
    float* hT     = cbuf + BB * HID;                  // 768*64  (k-major h)
    float* gpart  = hT + HID * 64;                    // 8*64*3072
    float* pval   = gpart + (size_t)KSPLIT * BB * NG; // 64*469
    int*   pidx   = (int*)(pval + BB * NBG);          // 64*469
    int*   tok    = pidx + BB * NBG;                  // 64
    float* hid_ws = (float*)(tok + BB);               // 64*512

    kc1<<<dim3(4, BB), 256, 0, stream>>>(feat, c1W, c1b, hid_ws);
    kc2<<<BB, 256, 0, stream>>>(hid_ws, c2W, c2b, out);
    kprep<<<dim3(HID * 64 / 256), 256, 0, stream>>>(feat, hT);

    for (int t = 0; t < TSTEPS; t++) {
        const float* h_in = (t == 0) ? feat : hbuf;
        kg1<<<dim3(48, KSPLIT), 256, 0, stream>>>(t, tok, emb, W_ih, W_hh, h_in, gpart);
        kc<<<dim3(192), 256, 0, stream>>>(t, gpart, b_ih, b_hh, cbuf, hbuf, hT);
        klog<<<dim3(NBG), 256, 0, stream>>>(hT, outW, outb, pval, pidx);
        kfin<<<BB, 256, 0, stream>>>(t, pval, pidx, tok, gen);
    }
}